// Round 15
// baseline (135.313 us; speedup 1.0000x reference)
//
#include <hip/hip_runtime.h>
#include <hip/hip_fp16.h>

#define NN 100000
#define NE 1600000
#define NB 391        // node buckets: node >> 8 (256 nodes/bucket, last=160)
#define NBLK 782      // edge chunks of CHUNK
#define CHUNK 2048
#define BT 1024       // k_bucket block size
#define PT 1024       // k_p2 block size
#define ASTR 8192     // arena stride/bucket; counts ~Bin(1.6M,256/1e5):
                      // mean 4096, sd 64 -> 8192 is +64 sd, cannot overflow

// ---- fp16 helpers ----------------------------------------------------------
__device__ __forceinline__ float h16lo(unsigned u) {
    return __half2float(__ushort_as_half((unsigned short)(u & 0xffffu)));
}
__device__ __forceinline__ float h16hi(unsigned u) {
    return __half2float(__ushort_as_half((unsigned short)(u >> 16)));
}
__device__ __forceinline__ unsigned short h16(float f) {
    return __half_as_ushort(__float2half(f));
}
__device__ __forceinline__ unsigned pack2h(float a, float b) {
    return (unsigned)h16(a) | ((unsigned)h16(b) << 16);
}

using f16x8  = __attribute__((ext_vector_type(8)))  _Float16;
using f32x16 = __attribute__((ext_vector_type(16))) float;

// ---------------------------------------------------------------------------
// B1: fused count + LDS counting-sort + coalesced arena write.
// CHUNK=2048 / NBLK=782 (R14 was 4096/391 -> 1.5 blocks/CU, occupancy-starved).
// ---------------------------------------------------------------------------
__global__ __launch_bounds__(BT) void k_bucket(
        const int* __restrict__ src, const int* __restrict__ dst,
        int* __restrict__ cur_d, int* __restrict__ cur_s,
        unsigned* __restrict__ bkd, unsigned char* __restrict__ bks) {
    __shared__ int hd[NB], hs[NB];            // hist, then LDS cursors
    __shared__ int bd[NB], bs[NB];            // claimed global bases
    __shared__ int od[NB], os[NB];            // local exclusive offsets
    __shared__ int t0[512], t1[512];          // scan temps
    __shared__ unsigned       sortd[CHUNK];   // dst-sorted packed entries
    __shared__ unsigned short sbkt [CHUNK];   // bucket id per entry (dst)
    __shared__ unsigned char  sorts[CHUNK];   // src-sorted bytes
    __shared__ unsigned short sbkts[CHUNK];   // bucket id per entry (src)

    int tid = threadIdx.x, blk = blockIdx.x;
    if (tid < NB) { hd[tid] = 0; hs[tid] = 0; }
    __syncthreads();

    int e0 = blk * CHUNK, ee = min(e0 + CHUNK, NE);
    int sv[2], dv[2]; bool va[2];
#pragma unroll
    for (int u = 0; u < 2; ++u) {
        int e = e0 + u * BT + tid;
        va[u] = e < ee;
        if (va[u]) {
            sv[u] = src[e]; dv[u] = dst[e];
            atomicAdd(&hd[dv[u] >> 8], 1);
            atomicAdd(&hs[sv[u] >> 8], 1);
        }
    }
    __syncthreads();

    if (tid < 512) {
        t0[tid] = tid < NB ? hd[tid] : 0;
        t1[tid] = tid < NB ? hs[tid] : 0;
    }
    __syncthreads();
    for (int off = 1; off < 512; off <<= 1) {
        int a = 0, b = 0;
        if (tid < 512 && tid >= off) { a = t0[tid - off]; b = t1[tid - off]; }
        __syncthreads();
        if (tid < 512) { t0[tid] += a; t1[tid] += b; }
        __syncthreads();
    }
    if (tid < NB) {
        int c = hd[tid], c2 = hs[tid];
        od[tid] = t0[tid] - c;
        os[tid] = t1[tid] - c2;
        bd[tid] = c  ? atomicAdd(&cur_d[tid], c)  : 0;
        bs[tid] = c2 ? atomicAdd(&cur_s[tid], c2) : 0;
        hd[tid] = od[tid];            // reuse as LDS cursors
        hs[tid] = os[tid];
    }
    __syncthreads();

#pragma unroll
    for (int u = 0; u < 2; ++u) if (va[u]) {
        int bu = dv[u] >> 8;
        int p = atomicAdd(&hd[bu], 1);
        sortd[p] = ((unsigned)(dv[u] & 255) << 17) | (unsigned)sv[u];
        sbkt[p]  = (unsigned short)bu;
        int bv = sv[u] >> 8;
        int q = atomicAdd(&hs[bv], 1);
        sorts[q] = (unsigned char)(sv[u] & 255);
        sbkts[q] = (unsigned short)bv;
    }
    __syncthreads();

    int n = ee - e0;
    for (int i = tid; i < n; i += BT) {
        int b1 = sbkt[i];
        bkd[b1 * ASTR + bd[b1] + (i - od[b1])] = sortd[i];
        int b2 = sbkts[i];
        bks[b2 * ASTR + bs[b2] + (i - os[b2])] = sorts[i];
    }
}

// ---------------------------------------------------------------------------
// B2 (FUSED scanb+p2d+p2s+norm+CVT): per-bucket csr base, in-degree counts,
// CSR start/scatter, normalizers, AND the xs fp16 table for this bucket's
// 256 nodes (dis held in LDS).  Block 0 additionally converts the weight
// tables.  (k_cvt kernel deleted; xs now aliases hws, NOT bkd.)
// ---------------------------------------------------------------------------
__global__ __launch_bounds__(PT) void k_p2(const unsigned* __restrict__ bkd,
                                           const unsigned char* __restrict__ bks,
                                           const int* __restrict__ cur_d,
                                           const int* __restrict__ cur_s,
                                           const float* __restrict__ x,
                                           int* __restrict__ cd,
                                           int* __restrict__ start,
                                           int* __restrict__ csr_s,
                                           float* __restrict__ dis,
                                           float* __restrict__ disg,
                                           unsigned short* __restrict__ xs,
                                           const float* __restrict__ W_xz,
                                           const float* __restrict__ W_xh,
                                           const float* __restrict__ W_gcn,
                                           unsigned short* __restrict__ BzT,
                                           unsigned short* __restrict__ BhT,
                                           unsigned short* __restrict__ WgT) {
    __shared__ int hist[256], scn[256], hsA[256];
    __shared__ float disL[256];
    __shared__ int red[PT];
    int b = blockIdx.x, tid = threadIdx.x;
    if (tid < 256) { hist[tid] = 0; hsA[tid] = 0; }
    int acc = 0;
    for (int i = tid; i < b; i += PT) acc += cur_d[i];
    red[tid] = acc;
    __syncthreads();
    for (int off = PT / 2; off > 0; off >>= 1) {
        if (tid < off) red[tid] += red[tid + off];
        __syncthreads();
    }
    int cb = red[0];

    int eb = b * ASTR, ee = eb + cur_d[b];
    for (int e = eb + tid; e < ee; e += PT)
        atomicAdd(&hist[bkd[e] >> 17], 1);
    int sb = b * ASTR, se = sb + cur_s[b];
    for (int e = sb + tid; e < se; e += PT)
        atomicAdd(&hsA[bks[e]], 1);
    __syncthreads();
    int c = (tid < 256) ? hist[tid] : 0;
    if (tid < 256) scn[tid] = c;
    __syncthreads();
    for (int off = 1; off < 256; off <<= 1) {
        int t = (tid < 256 && tid >= off) ? scn[tid - off] : 0;
        __syncthreads();
        if (tid < 256) scn[tid] += t;
        __syncthreads();
    }
    if (tid < 256) {
        int excl = scn[tid] - c;
        int node = (b << 8) + tid;
        if (node < NN) {
            cd[node] = c;
            start[node] = cb + excl;
            int oc = hsA[tid];
            float dv = oc > 0 ? rsqrtf((float)oc) : 0.0f;
            disL[tid]  = dv;
            dis[node]  = dv;
            disg[node] = rsqrtf((float)c + 1.0f);
        }
    }
    __syncthreads();              // all hsA reads done; disL visible
    if (tid < 256) hsA[tid] = cb + scn[tid] - c;   // reuse as csr cursor
    __syncthreads();
    for (int e = eb + tid; e < ee; e += PT) {
        unsigned pk = bkd[e];
        int p = atomicAdd(&hsA[pk >> 17], 1);
        csr_s[p] = (int)(pk & 0x1FFFFu);
    }

    // xs table for this bucket's nodes: xs[node][f] = fp16(dis[node]*x[node][f])
    int nbase = b << 8;
    for (int i = tid; i < 256 * 32; i += PT) {
        int nl = i >> 5, f = i & 31;
        int node = nbase + nl;
        if (node < NN)
            xs[node * 32 + f] = h16(x[node * 32 + f] * disL[nl]);
    }

    // weight tables (block 0 only; ~3K converts)
    if (b == 0) {
        for (int idx = tid; idx < 2048; idx += PT) {
            int f = idx >> 6, k = idx & 63;
            float vz = (k < 32) ? W_xz[k * 32 + f] : W_xz[1024 + (k - 32) * 32 + f];
            float vh = (k < 32) ? W_xh[k * 32 + f] : W_xh[1024 + (k - 32) * 32 + f];
            BzT[idx] = h16(vz);
            BhT[idx] = h16(vh);
        }
        for (int idx = tid; idx < 1024; idx += PT) {
            int f = idx >> 5, k = idx & 31;
            WgT[idx] = h16(W_gcn[k * 32 + f]);
        }
    }
}

// ---------------------------------------------------------------------------
// K_gath_lx: MERGED single-pass gather (R14, passing).  8 lanes/edge (uint2),
// 4 f32 accumulators, 2-step butterfly.  Writes Lx row * -dis[dst] (fp16).
// ---------------------------------------------------------------------------
__global__ __launch_bounds__(256) void k_gath_lx(const uint2* __restrict__ xs2,
                                                 const int* __restrict__ csr_s,
                                                 const int* __restrict__ start,
                                                 const int* __restrict__ cd,
                                                 const float* __restrict__ dis,
                                                 unsigned* __restrict__ Lxh) {
    int tid = threadIdx.x;
    int node = blockIdx.x * 8 + (tid >> 5);
    int lane = tid & 31, eoff = lane >> 3, c = lane & 7;
    int st = start[node], cn = cd[node];

    float a0 = 0.f, a1 = 0.f, a2 = 0.f, a3 = 0.f;
    for (int j = 0; j < cn; j += 8) {
        int e0 = j + eoff, e1 = j + 4 + eoff;
        int c0 = e0 < cn ? e0 : cn - 1;  float m0 = e0 < cn ? 1.0f : 0.0f;
        int c1 = e1 < cn ? e1 : cn - 1;  float m1 = e1 < cn ? 1.0f : 0.0f;
        int s0 = csr_s[st + c0], s1 = csr_s[st + c1];
        uint2 v0 = xs2[s0 * 8 + c];
        uint2 v1 = xs2[s1 * 8 + c];
        a0 = fmaf(m0, h16lo(v0.x), a0);  a1 = fmaf(m0, h16hi(v0.x), a1);
        a2 = fmaf(m0, h16lo(v0.y), a2);  a3 = fmaf(m0, h16hi(v0.y), a3);
        a0 = fmaf(m1, h16lo(v1.x), a0);  a1 = fmaf(m1, h16hi(v1.x), a1);
        a2 = fmaf(m1, h16lo(v1.y), a2);  a3 = fmaf(m1, h16hi(v1.y), a3);
    }
#pragma unroll
    for (int off = 8; off < 32; off <<= 1) {
        a0 += __shfl_xor(a0, off, 32);  a1 += __shfl_xor(a1, off, 32);
        a2 += __shfl_xor(a2, off, 32);  a3 += __shfl_xor(a3, off, 32);
    }
    if (lane < 8) {      // c == lane; features 4c..4c+3
        float w = -dis[node];
        Lxh[node * 16 + 2 * lane]     = pack2h(w * a0, w * a1);
        Lxh[node * 16 + 2 * lane + 1] = pack2h(w * a2, w * a3);
    }
}

// ---------------------------------------------------------------------------
// K_dmm: MFMA dense phase (R14, passing).
// ---------------------------------------------------------------------------
__global__ __launch_bounds__(256) void k_dmm(
        const float* __restrict__ x,
        const f16x8* __restrict__ Lxh,    // [node*4 + (c-2)*2 + hi]
        const f16x8* __restrict__ BzT,
        const f16x8* __restrict__ BhT,
        const f16x8* __restrict__ WgT,
        const float* __restrict__ b_xz, const float* __restrict__ b_hz,
        const float* __restrict__ b_xh, const float* __restrict__ b_hh,
        const float* __restrict__ disg,
        unsigned short* __restrict__ hws) {
    __shared__ unsigned short Hl[4 * 1280];   // per-wave 32 x 40 u16 (80B pad)
    int tid = threadIdx.x;
    int wv = blockIdx.x * 4 + (tid >> 6);
    if (wv > 3124) wv = 3124;                 // dup tail wave: same writes, safe
    int l = tid & 63, mrow = l & 31, hi = l >> 5;
    int n0 = wv * 32;
    unsigned short* Hw = Hl + (tid >> 6) * 1280;

    f32x16 accz = {}, acct = {};
    const float* xrow = x + (size_t)(n0 + mrow) * 32;
#pragma unroll
    for (int c = 0; c < 2; ++c) {
        f16x8 a;
        const float* p = xrow + c * 16 + hi * 8;
#pragma unroll
        for (int e = 0; e < 8; ++e) a[e] = (_Float16)p[e];
        accz = __builtin_amdgcn_mfma_f32_32x32x16_f16(a, BzT[mrow * 8 + c * 2 + hi], accz, 0, 0, 0);
        acct = __builtin_amdgcn_mfma_f32_32x32x16_f16(a, BhT[mrow * 8 + c * 2 + hi], acct, 0, 0, 0);
    }
    const f16x8* Lrow = Lxh + (size_t)(n0 + mrow) * 4;
#pragma unroll
    for (int c = 2; c < 4; ++c) {
        f16x8 a = Lrow[(c - 2) * 2 + hi];
        accz = __builtin_amdgcn_mfma_f32_32x32x16_f16(a, BzT[mrow * 8 + c * 2 + hi], accz, 0, 0, 0);
        acct = __builtin_amdgcn_mfma_f32_32x32x16_f16(a, BhT[mrow * 8 + c * 2 + hi], acct, 0, 0, 0);
    }
    float bz = b_xz[mrow] + b_hz[mrow];
    float bh = b_xh[mrow] + b_hh[mrow];
#pragma unroll
    for (int j = 0; j < 16; ++j) {
        float z = accz[j] + bz, t = acct[j] + bh;
        float Z = 1.0f / (1.0f + expf(-z));
        float H = (1.0f - Z) * tanhf(t);
        int r = (j & 3) + 8 * (j >> 2) + 4 * hi;
        Hw[r * 40 + mrow] = h16(H);          // H^T staging (row=node, col=f)
    }
    f32x16 acch = {};
#pragma unroll
    for (int c = 0; c < 2; ++c) {
        f16x8 hfrag = *reinterpret_cast<const f16x8*>(&Hw[mrow * 40 + c * 16 + hi * 8]);
        acch = __builtin_amdgcn_mfma_f32_32x32x16_f16(hfrag, WgT[mrow * 4 + c * 2 + hi], acch, 0, 0, 0);
    }
#pragma unroll
    for (int j = 0; j < 16; ++j) {
        int r = (j & 3) + 8 * (j >> 2) + 4 * hi;
        int node = n0 + r;
        hws[node * 32 + mrow] = h16(disg[node] * acch[j]);
    }
}

// ---------------------------------------------------------------------------
// K_gath_h: MERGED single-pass gather + FULL fused epilogue (R14, passing).
// ---------------------------------------------------------------------------
__global__ __launch_bounds__(256) void k_gath_h(const uint2* __restrict__ hws2,
                                                const int* __restrict__ csr_s,
                                                const int* __restrict__ start,
                                                const int* __restrict__ cd,
                                                const float* __restrict__ disg,
                                                const float* __restrict__ b_gcn,
                                                const float* __restrict__ W_lin,
                                                const float* __restrict__ b_lin,
                                                float* __restrict__ out) {
    int tid = threadIdx.x;
    int node = blockIdx.x * 8 + (tid >> 5);
    int lane = tid & 31, eoff = lane >> 3, c = lane & 7;
    int st = start[node], cn = cd[node];

    float a0 = 0.f, a1 = 0.f, a2 = 0.f, a3 = 0.f;
    for (int j = 0; j < cn; j += 8) {
        int e0 = j + eoff, e1 = j + 4 + eoff;
        int c0 = e0 < cn ? e0 : cn - 1;  float m0 = e0 < cn ? 1.0f : 0.0f;
        int c1 = e1 < cn ? e1 : cn - 1;  float m1 = e1 < cn ? 1.0f : 0.0f;
        int s0 = csr_s[st + c0], s1 = csr_s[st + c1];
        uint2 v0 = hws2[s0 * 8 + c];
        uint2 v1 = hws2[s1 * 8 + c];
        a0 = fmaf(m0, h16lo(v0.x), a0);  a1 = fmaf(m0, h16hi(v0.x), a1);
        a2 = fmaf(m0, h16lo(v0.y), a2);  a3 = fmaf(m0, h16hi(v0.y), a3);
        a0 = fmaf(m1, h16lo(v1.x), a0);  a1 = fmaf(m1, h16hi(v1.x), a1);
        a2 = fmaf(m1, h16lo(v1.y), a2);  a3 = fmaf(m1, h16hi(v1.y), a3);
    }
#pragma unroll
    for (int off = 8; off < 32; off <<= 1) {
        a0 += __shfl_xor(a0, off, 32);  a1 += __shfl_xor(a1, off, 32);
        a2 += __shfl_xor(a2, off, 32);  a3 += __shfl_xor(a3, off, 32);
    }
    float p = 0.0f;
    if (lane < 8) {      // c == lane; features f0 = 4c
        uint2 sv = hws2[node * 8 + lane];   // self row (pre-scaled by disg)
        float dg = disg[node];
        int f0 = 4 * lane;
        float h0 = dg * (a0 + h16lo(sv.x)) + b_gcn[f0];
        float h1 = dg * (a1 + h16hi(sv.x)) + b_gcn[f0 + 1];
        float h2 = dg * (a2 + h16lo(sv.y)) + b_gcn[f0 + 2];
        float h3 = dg * (a3 + h16hi(sv.y)) + b_gcn[f0 + 3];
        p = fmaxf(h0, 0.0f) * W_lin[f0]
          + fmaxf(h1, 0.0f) * W_lin[f0 + 1]
          + fmaxf(h2, 0.0f) * W_lin[f0 + 2]
          + fmaxf(h3, 0.0f) * W_lin[f0 + 3];
    }
    p += __shfl_xor(p, 1, 32);
    p += __shfl_xor(p, 2, 32);
    p += __shfl_xor(p, 4, 32);
    if (lane == 0) out[node] = p + b_lin[0];
}

extern "C" void kernel_launch(void* const* d_in, const int* in_sizes, int n_in,
                              void* d_out, int out_size, void* d_ws, size_t ws_size,
                              hipStream_t stream) {
    const float* x     = (const float*)d_in[0];
    const int*   ei    = (const int*)d_in[1];
    const int*   src   = ei;
    const int*   dst   = ei + NE;
    const float* W_xz  = (const float*)d_in[2];
    const float* b_xz  = (const float*)d_in[3];
    const float* b_hz  = (const float*)d_in[5];
    // W_xr/b_xr/W_hr/b_hr (d_in[6..9]) are dead: R only multiplies H0 == 0.
    const float* W_xh  = (const float*)d_in[10];
    const float* b_xh  = (const float*)d_in[11];
    const float* b_hh  = (const float*)d_in[13];
    const float* W_gcn = (const float*)d_in[14];
    const float* b_gcn = (const float*)d_in[15];
    const float* W_lin = (const float*)d_in[16];
    const float* b_lin = (const float*)d_in[17];
    float* out = (float*)d_out;

    // Workspace (4B words), ~37.2 MB.  Only cur_d/cur_s need zeroing (3.1KB).
    // ALIAS AUDIT (stream order): xs aliases hws (16N words each).
    //   k_p2 WRITES xs -> k_gath_lx READS xs (last reader) -> k_dmm WRITES
    //   hws -> k_gath_h READS hws.  No overlap with bkd (k_p2 reads it).
    // Alignment: hws/xs @500,784 w = 2,003,136 B (8B ok for uint2);
    //   Lxh @2,100,784 w = 8,403,136 B (%16==0, f16x8 ok);
    //   BzT tail @9,304,624 w (%4==0, f16x8 16B ok: *4=37,218,496 %16==0).
    // Sizes (R9 lesson): BzT/BhT = 1024 words (2048 ushorts), WgT = 512.
    int* w = (int*)d_ws;
    int* cur_d = w;                       w += 392;
    int* cur_s = w;                       w += 392;
    int* cd    = w;                       w += NN;
    int* start = w;                       w += NN;
    float* dis  = (float*)w;              w += NN;
    float* disg = (float*)w;              w += NN;
    unsigned short* hws = (unsigned short*)w;  w += 16 * NN;    // 32 fp16/node
    unsigned* Lxh = (unsigned*)w;         w += 16 * NN;         // 32 fp16/node
    unsigned* bkd = (unsigned*)w;         w += NB * ASTR;       // 3,203,072
    unsigned char* bks = (unsigned char*)w; w += (NB * ASTR) / 4;
    int* csr_s = w;                       w += NE;
    unsigned short* BzT = (unsigned short*)w; w += 1024;        // 32f x 64k
    unsigned short* BhT = (unsigned short*)w; w += 1024;
    unsigned short* WgT = (unsigned short*)w; w += 512;         // 32f x 32k
    unsigned short* xs = hws;                                   // alias (see audit)

    hipMemsetAsync(cur_d, 0, 784 * sizeof(int), stream);

    k_bucket <<<NBLK, BT, 0, stream>>>(src, dst, cur_d, cur_s, bkd, bks);
    k_p2     <<<NB, PT, 0, stream>>>(bkd, bks, cur_d, cur_s, x,
                                     cd, start, csr_s, dis, disg, xs,
                                     W_xz, W_xh, W_gcn, BzT, BhT, WgT);
    k_gath_lx<<<NN / 8, 256, 0, stream>>>((const uint2*)xs, csr_s, start, cd,
                                          dis, Lxh);
    k_dmm    <<<782, 256, 0, stream>>>(x, (const f16x8*)Lxh, (const f16x8*)BzT,
                                       (const f16x8*)BhT, (const f16x8*)WgT,
                                       b_xz, b_hz, b_xh, b_hh, disg, hws);
    k_gath_h <<<NN / 8, 256, 0, stream>>>((const uint2*)hws, csr_s, start, cd,
                                          disg, b_gcn, W_lin, b_lin, out);
}

// Round 16
// 122.941 us; speedup vs baseline: 1.1006x; 1.1006x over previous
//
#include <hip/hip_runtime.h>
#include <hip/hip_fp16.h>

#define NN 100000
#define NE 1600000
#define NB 391        // node buckets: node >> 8 (256 nodes/bucket, last=160)
#define NBLK 391      // edge chunks of CHUNK
#define CHUNK 4096
#define BT 1024       // k_bucket block size
#define PT 1024       // k_p2 block size
#define ASTR 8192     // arena stride/bucket; counts ~Bin(1.6M,256/1e5):
                      // mean 4096, sd 64 -> 8192 is +64 sd, cannot overflow

// ---- fp16 helpers ----------------------------------------------------------
__device__ __forceinline__ float h16lo(unsigned u) {
    return __half2float(__ushort_as_half((unsigned short)(u & 0xffffu)));
}
__device__ __forceinline__ float h16hi(unsigned u) {
    return __half2float(__ushort_as_half((unsigned short)(u >> 16)));
}
__device__ __forceinline__ unsigned short h16(float f) {
    return __half_as_ushort(__float2half(f));
}
__device__ __forceinline__ unsigned pack2h(float a, float b) {
    return (unsigned)h16(a) | ((unsigned)h16(b) << 16);
}

using f16x8  = __attribute__((ext_vector_type(8)))  _Float16;
using f32x16 = __attribute__((ext_vector_type(16))) float;

// ---------------------------------------------------------------------------
// B1: fused count + LDS counting-sort + coalesced arena write (R12/R14,
// passing at 4096/391; R15's 2048/782 split REGRESSED — fixed scan cost
// doubles and write runs shorten).
// ---------------------------------------------------------------------------
__global__ __launch_bounds__(BT) void k_bucket(
        const int* __restrict__ src, const int* __restrict__ dst,
        int* __restrict__ cur_d, int* __restrict__ cur_s,
        unsigned* __restrict__ bkd, unsigned char* __restrict__ bks) {
    __shared__ int hd[NB], hs[NB];            // hist, then LDS cursors
    __shared__ int bd[NB], bs[NB];            // claimed global bases
    __shared__ int od[NB], os[NB];            // local exclusive offsets
    __shared__ int t0[512], t1[512];          // scan temps
    __shared__ unsigned       sortd[CHUNK];   // dst-sorted packed entries
    __shared__ unsigned short sbkt [CHUNK];   // bucket id per entry (dst)
    __shared__ unsigned char  sorts[CHUNK];   // src-sorted bytes
    __shared__ unsigned short sbkts[CHUNK];   // bucket id per entry (src)

    int tid = threadIdx.x, blk = blockIdx.x;
    if (tid < NB) { hd[tid] = 0; hs[tid] = 0; }
    __syncthreads();

    int e0 = blk * CHUNK, ee = min(e0 + CHUNK, NE);
    int sv[4], dv[4]; bool va[4];
#pragma unroll
    for (int u = 0; u < 4; ++u) {
        int e = e0 + u * BT + tid;
        va[u] = e < ee;
        if (va[u]) {
            sv[u] = src[e]; dv[u] = dst[e];
            atomicAdd(&hd[dv[u] >> 8], 1);
            atomicAdd(&hs[sv[u] >> 8], 1);
        }
    }
    __syncthreads();

    if (tid < 512) {
        t0[tid] = tid < NB ? hd[tid] : 0;
        t1[tid] = tid < NB ? hs[tid] : 0;
    }
    __syncthreads();
    for (int off = 1; off < 512; off <<= 1) {
        int a = 0, b = 0;
        if (tid < 512 && tid >= off) { a = t0[tid - off]; b = t1[tid - off]; }
        __syncthreads();
        if (tid < 512) { t0[tid] += a; t1[tid] += b; }
        __syncthreads();
    }
    if (tid < NB) {
        int c = hd[tid], c2 = hs[tid];
        od[tid] = t0[tid] - c;
        os[tid] = t1[tid] - c2;
        bd[tid] = c  ? atomicAdd(&cur_d[tid], c)  : 0;
        bs[tid] = c2 ? atomicAdd(&cur_s[tid], c2) : 0;
        hd[tid] = od[tid];            // reuse as LDS cursors
        hs[tid] = os[tid];
    }
    __syncthreads();

#pragma unroll
    for (int u = 0; u < 4; ++u) if (va[u]) {
        int bu = dv[u] >> 8;
        int p = atomicAdd(&hd[bu], 1);
        sortd[p] = ((unsigned)(dv[u] & 255) << 17) | (unsigned)sv[u];
        sbkt[p]  = (unsigned short)bu;
        int bv = sv[u] >> 8;
        int q = atomicAdd(&hs[bv], 1);
        sorts[q] = (unsigned char)(sv[u] & 255);
        sbkts[q] = (unsigned short)bv;
    }
    __syncthreads();

    int n = ee - e0;
    for (int i = tid; i < n; i += BT) {
        int b1 = sbkt[i];
        bkd[b1 * ASTR + bd[b1] + (i - od[b1])] = sortd[i];
        int b2 = sbkts[i];
        bks[b2 * ASTR + bs[b2] + (i - os[b2])] = sorts[i];
    }
}

// ---------------------------------------------------------------------------
// B2 (FUSED scanb+p2d+p2s+norm), 1024 threads (R13/R14, passing).
// ---------------------------------------------------------------------------
__global__ __launch_bounds__(PT) void k_p2(const unsigned* __restrict__ bkd,
                                           const unsigned char* __restrict__ bks,
                                           const int* __restrict__ cur_d,
                                           const int* __restrict__ cur_s,
                                           int* __restrict__ cd,
                                           int* __restrict__ start,
                                           int* __restrict__ csr_s,
                                           float* __restrict__ dis,
                                           float* __restrict__ disg) {
    __shared__ int hist[256], scn[256], hsA[256];
    __shared__ int red[PT];
    int b = blockIdx.x, tid = threadIdx.x;
    if (tid < 256) { hist[tid] = 0; hsA[tid] = 0; }
    int acc = 0;
    for (int i = tid; i < b; i += PT) acc += cur_d[i];
    red[tid] = acc;
    __syncthreads();
    for (int off = PT / 2; off > 0; off >>= 1) {
        if (tid < off) red[tid] += red[tid + off];
        __syncthreads();
    }
    int cb = red[0];

    int eb = b * ASTR, ee = eb + cur_d[b];
    for (int e = eb + tid; e < ee; e += PT)
        atomicAdd(&hist[bkd[e] >> 17], 1);
    int sb = b * ASTR, se = sb + cur_s[b];
    for (int e = sb + tid; e < se; e += PT)
        atomicAdd(&hsA[bks[e]], 1);
    __syncthreads();
    int c = (tid < 256) ? hist[tid] : 0;
    if (tid < 256) scn[tid] = c;
    __syncthreads();
    for (int off = 1; off < 256; off <<= 1) {
        int t = (tid < 256 && tid >= off) ? scn[tid - off] : 0;
        __syncthreads();
        if (tid < 256) scn[tid] += t;
        __syncthreads();
    }
    if (tid < 256) {
        int excl = scn[tid] - c;
        int node = (b << 8) + tid;
        if (node < NN) {
            cd[node] = c;
            start[node] = cb + excl;
            int oc = hsA[tid];
            dis[node]  = oc > 0 ? rsqrtf((float)oc) : 0.0f;
            disg[node] = rsqrtf((float)c + 1.0f);
        }
    }
    __syncthreads();              // all hsA reads done
    if (tid < 256) hsA[tid] = cb + scn[tid] - c;   // reuse as csr cursor
    __syncthreads();
    for (int e = eb + tid; e < ee; e += PT) {
        unsigned pk = bkd[e];
        int p = atomicAdd(&hsA[pk >> 17], 1);
        csr_s[p] = (int)(pk & 0x1FFFFu);
    }
}

// ---------------------------------------------------------------------------
// K_cvt (+wcvt in the extra block): SINGLE merged fp16 table (R14, passing).
// ---------------------------------------------------------------------------
__global__ __launch_bounds__(256) void k_cvt(const float* __restrict__ x,
                                             const float* __restrict__ dis,
                                             unsigned short* __restrict__ xs,
                                             const float* __restrict__ W_xz,
                                             const float* __restrict__ W_xh,
                                             const float* __restrict__ W_gcn,
                                             unsigned short* __restrict__ BzT,
                                             unsigned short* __restrict__ BhT,
                                             unsigned short* __restrict__ WgT) {
    int tid = threadIdx.x;
    int i = blockIdx.x * 256 + tid;
    if (i < NN * 32) {
        xs[i] = h16(x[i] * dis[i >> 5]);
    } else if (blockIdx.x == (NN * 32) / 256) {
        for (int idx = tid; idx < 2048; idx += 256) {
            int f = idx >> 6, k = idx & 63;
            float vz = (k < 32) ? W_xz[k * 32 + f] : W_xz[1024 + (k - 32) * 32 + f];
            float vh = (k < 32) ? W_xh[k * 32 + f] : W_xh[1024 + (k - 32) * 32 + f];
            BzT[idx] = h16(vz);
            BhT[idx] = h16(vh);
        }
        for (int idx = tid; idx < 1024; idx += 256) {
            int f = idx >> 5, k = idx & 31;
            WgT[idx] = h16(W_gcn[k * 32 + f]);
        }
    }
}

// ---------------------------------------------------------------------------
// K_gath_lx: merged single-pass gather, UNMASKED main loop + masked tail.
// At mean deg 16 most iterations now carry zero mask/clamp VALU ops.
// ---------------------------------------------------------------------------
__global__ __launch_bounds__(256) void k_gath_lx(const uint2* __restrict__ xs2,
                                                 const int* __restrict__ csr_s,
                                                 const int* __restrict__ start,
                                                 const int* __restrict__ cd,
                                                 const float* __restrict__ dis,
                                                 unsigned* __restrict__ Lxh) {
    int tid = threadIdx.x;
    int node = blockIdx.x * 8 + (tid >> 5);
    int lane = tid & 31, eoff = lane >> 3, c = lane & 7;
    int st = start[node], cn = cd[node];

    float a0 = 0.f, a1 = 0.f, a2 = 0.f, a3 = 0.f;
    int full = cn & ~7;
    int j = 0;
    for (; j < full; j += 8) {             // unmasked: all 8 edges valid
        int s0 = csr_s[st + j + eoff];
        int s1 = csr_s[st + j + 4 + eoff];
        uint2 v0 = xs2[s0 * 8 + c];
        uint2 v1 = xs2[s1 * 8 + c];
        a0 += h16lo(v0.x);  a1 += h16hi(v0.x);
        a2 += h16lo(v0.y);  a3 += h16hi(v0.y);
        a0 += h16lo(v1.x);  a1 += h16hi(v1.x);
        a2 += h16lo(v1.y);  a3 += h16hi(v1.y);
    }
    if (j < cn) {                          // one masked tail batch
        int e0 = j + eoff, e1 = j + 4 + eoff;
        int c0 = e0 < cn ? e0 : cn - 1;  float m0 = e0 < cn ? 1.0f : 0.0f;
        int c1 = e1 < cn ? e1 : cn - 1;  float m1 = e1 < cn ? 1.0f : 0.0f;
        int s0 = csr_s[st + c0], s1 = csr_s[st + c1];
        uint2 v0 = xs2[s0 * 8 + c];
        uint2 v1 = xs2[s1 * 8 + c];
        a0 = fmaf(m0, h16lo(v0.x), a0);  a1 = fmaf(m0, h16hi(v0.x), a1);
        a2 = fmaf(m0, h16lo(v0.y), a2);  a3 = fmaf(m0, h16hi(v0.y), a3);
        a0 = fmaf(m1, h16lo(v1.x), a0);  a1 = fmaf(m1, h16hi(v1.x), a1);
        a2 = fmaf(m1, h16lo(v1.y), a2);  a3 = fmaf(m1, h16hi(v1.y), a3);
    }
#pragma unroll
    for (int off = 8; off < 32; off <<= 1) {
        a0 += __shfl_xor(a0, off, 32);  a1 += __shfl_xor(a1, off, 32);
        a2 += __shfl_xor(a2, off, 32);  a3 += __shfl_xor(a3, off, 32);
    }
    if (lane < 8) {      // c == lane; features 4c..4c+3
        float w = -dis[node];
        Lxh[node * 16 + 2 * lane]     = pack2h(w * a0, w * a1);
        Lxh[node * 16 + 2 * lane + 1] = pack2h(w * a2, w * a3);
    }
}

// ---------------------------------------------------------------------------
// K_dmm: MFMA dense phase (R14, passing).
// ---------------------------------------------------------------------------
__global__ __launch_bounds__(256) void k_dmm(
        const float* __restrict__ x,
        const f16x8* __restrict__ Lxh,    // [node*4 + (c-2)*2 + hi]
        const f16x8* __restrict__ BzT,
        const f16x8* __restrict__ BhT,
        const f16x8* __restrict__ WgT,
        const float* __restrict__ b_xz, const float* __restrict__ b_hz,
        const float* __restrict__ b_xh, const float* __restrict__ b_hh,
        const float* __restrict__ disg,
        unsigned short* __restrict__ hws) {
    __shared__ unsigned short Hl[4 * 1280];   // per-wave 32 x 40 u16 (80B pad)
    int tid = threadIdx.x;
    int wv = blockIdx.x * 4 + (tid >> 6);
    if (wv > 3124) wv = 3124;                 // dup tail wave: same writes, safe
    int l = tid & 63, mrow = l & 31, hi = l >> 5;
    int n0 = wv * 32;
    unsigned short* Hw = Hl + (tid >> 6) * 1280;

    f32x16 accz = {}, acct = {};
    const float* xrow = x + (size_t)(n0 + mrow) * 32;
#pragma unroll
    for (int c = 0; c < 2; ++c) {
        f16x8 a;
        const float* p = xrow + c * 16 + hi * 8;
#pragma unroll
        for (int e = 0; e < 8; ++e) a[e] = (_Float16)p[e];
        accz = __builtin_amdgcn_mfma_f32_32x32x16_f16(a, BzT[mrow * 8 + c * 2 + hi], accz, 0, 0, 0);
        acct = __builtin_amdgcn_mfma_f32_32x32x16_f16(a, BhT[mrow * 8 + c * 2 + hi], acct, 0, 0, 0);
    }
    const f16x8* Lrow = Lxh + (size_t)(n0 + mrow) * 4;
#pragma unroll
    for (int c = 2; c < 4; ++c) {
        f16x8 a = Lrow[(c - 2) * 2 + hi];
        accz = __builtin_amdgcn_mfma_f32_32x32x16_f16(a, BzT[mrow * 8 + c * 2 + hi], accz, 0, 0, 0);
        acct = __builtin_amdgcn_mfma_f32_32x32x16_f16(a, BhT[mrow * 8 + c * 2 + hi], acct, 0, 0, 0);
    }
    float bz = b_xz[mrow] + b_hz[mrow];
    float bh = b_xh[mrow] + b_hh[mrow];
#pragma unroll
    for (int j = 0; j < 16; ++j) {
        float z = accz[j] + bz, t = acct[j] + bh;
        float Z = 1.0f / (1.0f + expf(-z));
        float H = (1.0f - Z) * tanhf(t);
        int r = (j & 3) + 8 * (j >> 2) + 4 * hi;
        Hw[r * 40 + mrow] = h16(H);          // H^T staging (row=node, col=f)
    }
    f32x16 acch = {};
#pragma unroll
    for (int c = 0; c < 2; ++c) {
        f16x8 hfrag = *reinterpret_cast<const f16x8*>(&Hw[mrow * 40 + c * 16 + hi * 8]);
        acch = __builtin_amdgcn_mfma_f32_32x32x16_f16(hfrag, WgT[mrow * 4 + c * 2 + hi], acch, 0, 0, 0);
    }
#pragma unroll
    for (int j = 0; j < 16; ++j) {
        int r = (j & 3) + 8 * (j >> 2) + 4 * hi;
        int node = n0 + r;
        hws[node * 32 + mrow] = h16(disg[node] * acch[j]);
    }
}

// ---------------------------------------------------------------------------
// K_gath_h: merged gather + full fused epilogue, unmasked main + masked tail.
// ---------------------------------------------------------------------------
__global__ __launch_bounds__(256) void k_gath_h(const uint2* __restrict__ hws2,
                                                const int* __restrict__ csr_s,
                                                const int* __restrict__ start,
                                                const int* __restrict__ cd,
                                                const float* __restrict__ disg,
                                                const float* __restrict__ b_gcn,
                                                const float* __restrict__ W_lin,
                                                const float* __restrict__ b_lin,
                                                float* __restrict__ out) {
    int tid = threadIdx.x;
    int node = blockIdx.x * 8 + (tid >> 5);
    int lane = tid & 31, eoff = lane >> 3, c = lane & 7;
    int st = start[node], cn = cd[node];

    float a0 = 0.f, a1 = 0.f, a2 = 0.f, a3 = 0.f;
    int full = cn & ~7;
    int j = 0;
    for (; j < full; j += 8) {             // unmasked: all 8 edges valid
        int s0 = csr_s[st + j + eoff];
        int s1 = csr_s[st + j + 4 + eoff];
        uint2 v0 = hws2[s0 * 8 + c];
        uint2 v1 = hws2[s1 * 8 + c];
        a0 += h16lo(v0.x);  a1 += h16hi(v0.x);
        a2 += h16lo(v0.y);  a3 += h16hi(v0.y);
        a0 += h16lo(v1.x);  a1 += h16hi(v1.x);
        a2 += h16lo(v1.y);  a3 += h16hi(v1.y);
    }
    if (j < cn) {                          // one masked tail batch
        int e0 = j + eoff, e1 = j + 4 + eoff;
        int c0 = e0 < cn ? e0 : cn - 1;  float m0 = e0 < cn ? 1.0f : 0.0f;
        int c1 = e1 < cn ? e1 : cn - 1;  float m1 = e1 < cn ? 1.0f : 0.0f;
        int s0 = csr_s[st + c0], s1 = csr_s[st + c1];
        uint2 v0 = hws2[s0 * 8 + c];
        uint2 v1 = hws2[s1 * 8 + c];
        a0 = fmaf(m0, h16lo(v0.x), a0);  a1 = fmaf(m0, h16hi(v0.x), a1);
        a2 = fmaf(m0, h16lo(v0.y), a2);  a3 = fmaf(m0, h16hi(v0.y), a3);
        a0 = fmaf(m1, h16lo(v1.x), a0);  a1 = fmaf(m1, h16hi(v1.x), a1);
        a2 = fmaf(m1, h16lo(v1.y), a2);  a3 = fmaf(m1, h16hi(v1.y), a3);
    }
#pragma unroll
    for (int off = 8; off < 32; off <<= 1) {
        a0 += __shfl_xor(a0, off, 32);  a1 += __shfl_xor(a1, off, 32);
        a2 += __shfl_xor(a2, off, 32);  a3 += __shfl_xor(a3, off, 32);
    }
    float p = 0.0f;
    if (lane < 8) {      // c == lane; features f0 = 4c
        uint2 sv = hws2[node * 8 + lane];   // self row (pre-scaled by disg)
        float dg = disg[node];
        int f0 = 4 * lane;
        float h0 = dg * (a0 + h16lo(sv.x)) + b_gcn[f0];
        float h1 = dg * (a1 + h16hi(sv.x)) + b_gcn[f0 + 1];
        float h2 = dg * (a2 + h16lo(sv.y)) + b_gcn[f0 + 2];
        float h3 = dg * (a3 + h16hi(sv.y)) + b_gcn[f0 + 3];
        p = fmaxf(h0, 0.0f) * W_lin[f0]
          + fmaxf(h1, 0.0f) * W_lin[f0 + 1]
          + fmaxf(h2, 0.0f) * W_lin[f0 + 2]
          + fmaxf(h3, 0.0f) * W_lin[f0 + 3];
    }
    p += __shfl_xor(p, 1, 32);
    p += __shfl_xor(p, 2, 32);
    p += __shfl_xor(p, 4, 32);
    if (lane == 0) out[node] = p + b_lin[0];
}

extern "C" void kernel_launch(void* const* d_in, const int* in_sizes, int n_in,
                              void* d_out, int out_size, void* d_ws, size_t ws_size,
                              hipStream_t stream) {
    const float* x     = (const float*)d_in[0];
    const int*   ei    = (const int*)d_in[1];
    const int*   src   = ei;
    const int*   dst   = ei + NE;
    const float* W_xz  = (const float*)d_in[2];
    const float* b_xz  = (const float*)d_in[3];
    const float* b_hz  = (const float*)d_in[5];
    // W_xr/b_xr/W_hr/b_hr (d_in[6..9]) are dead: R only multiplies H0 == 0.
    const float* W_xh  = (const float*)d_in[10];
    const float* b_xh  = (const float*)d_in[11];
    const float* b_hh  = (const float*)d_in[13];
    const float* W_gcn = (const float*)d_in[14];
    const float* b_gcn = (const float*)d_in[15];
    const float* W_lin = (const float*)d_in[16];
    const float* b_lin = (const float*)d_in[17];
    float* out = (float*)d_out;

    // Workspace (4B words), ~36.8 MB (R14 layout).  Only cur_d/cur_s zeroed.
    // Aliases: xs (16N words) overlays bkd arena (dead after k_p2).
    int* w = (int*)d_ws;
    int* cur_d = w;                       w += 392;
    int* cur_s = w;                       w += 392;
    int* cd    = w;                       w += NN;
    int* start = w;                       w += NN;
    float* dis  = (float*)w;              w += NN;
    float* disg = (float*)w;              w += NN;
    unsigned short* hws = (unsigned short*)w;  w += 16 * NN;    // 32 fp16/node
    unsigned* Lxh = (unsigned*)w;         w += 16 * NN;         // 32 fp16/node
    unsigned* bkd = (unsigned*)w;         w += NB * ASTR;       // 3,203,072
    unsigned char* bks = (unsigned char*)w; w += (NB * ASTR) / 4;
    int* csr_s = w;                       w += NE;
    unsigned short* BzT = (unsigned short*)w; w += 1024;        // 32f x 64k
    unsigned short* BhT = (unsigned short*)w; w += 1024;
    unsigned short* WgT = (unsigned short*)w; w += 512;         // 32f x 32k
    unsigned short* xs = (unsigned short*)bkd;                  // alias

    hipMemsetAsync(cur_d, 0, 784 * sizeof(int), stream);

    k_bucket <<<NBLK, BT, 0, stream>>>(src, dst, cur_d, cur_s, bkd, bks);
    k_p2     <<<NB, PT, 0, stream>>>(bkd, bks, cur_d, cur_s,
                                     cd, start, csr_s, dis, disg);
    k_cvt    <<<(NN * 32) / 256 + 1, 256, 0, stream>>>(x, dis, xs,
                                      W_xz, W_xh, W_gcn, BzT, BhT, WgT);
    k_gath_lx<<<NN / 8, 256, 0, stream>>>((const uint2*)xs, csr_s, start, cd,
                                          dis, Lxh);
    k_dmm    <<<782, 256, 0, stream>>>(x, (const f16x8*)Lxh, (const f16x8*)BzT,
                                       (const f16x8*)BhT, (const f16x8*)WgT,
                                       b_xz, b_hz, b_xh, b_hh, disg, hws);
    k_gath_h <<<NN / 8, 256, 0, stream>>>((const uint2*)hws, csr_s, start, cd,
                                          disg, b_gcn, W_lin, b_lin, out);
}

// Round 17
// 120.498 us; speedup vs baseline: 1.1229x; 1.0203x over previous
//
#include <hip/hip_runtime.h>
#include <hip/hip_fp16.h>

#define NN 100000
#define NE 1600000
#define NB 391        // node buckets: node >> 8 (256 nodes/bucket, last=160)
#define NBLK 391      // edge chunks of CHUNK
#define CHUNK 4096
#define BT 1024       // k_bucket block size
#define PT 1024       // k_p2 block size
#define ASTR 8192     // arena stride/bucket; counts ~Bin(1.6M,256/1e5):
                      // mean 4096, sd 64 -> 8192 is +64 sd, cannot overflow

// ---- fp16 helpers ----------------------------------------------------------
__device__ __forceinline__ float h16lo(unsigned u) {
    return __half2float(__ushort_as_half((unsigned short)(u & 0xffffu)));
}
__device__ __forceinline__ float h16hi(unsigned u) {
    return __half2float(__ushort_as_half((unsigned short)(u >> 16)));
}
__device__ __forceinline__ unsigned short h16(float f) {
    return __half_as_ushort(__float2half(f));
}
__device__ __forceinline__ unsigned pack2h(float a, float b) {
    return (unsigned)h16(a) | ((unsigned)h16(b) << 16);
}
__device__ __forceinline__ __half2 u2h2(unsigned u) {
    union { unsigned u; __half2 h; } cv; cv.u = u; return cv.h;
}

using f16x8  = __attribute__((ext_vector_type(8)))  _Float16;
using f32x16 = __attribute__((ext_vector_type(16))) float;

// ---------------------------------------------------------------------------
// K0: zero the 784 cursor ints (replaces hipMemsetAsync -> runtime
// fillBufferAligned, which profiled at ~44 us in-stream).
// ---------------------------------------------------------------------------
__global__ __launch_bounds__(1024) void k_zero(int* __restrict__ p) {
    int i = threadIdx.x;
    if (i < 784) p[i] = 0;
}

// ---------------------------------------------------------------------------
// B1: fused count + LDS counting-sort + coalesced arena write (R12/R14/R16).
// ---------------------------------------------------------------------------
__global__ __launch_bounds__(BT) void k_bucket(
        const int* __restrict__ src, const int* __restrict__ dst,
        int* __restrict__ cur_d, int* __restrict__ cur_s,
        unsigned* __restrict__ bkd, unsigned char* __restrict__ bks) {
    __shared__ int hd[NB], hs[NB];            // hist, then LDS cursors
    __shared__ int bd[NB], bs[NB];            // claimed global bases
    __shared__ int od[NB], os[NB];            // local exclusive offsets
    __shared__ int t0[512], t1[512];          // scan temps
    __shared__ unsigned       sortd[CHUNK];   // dst-sorted packed entries
    __shared__ unsigned short sbkt [CHUNK];   // bucket id per entry (dst)
    __shared__ unsigned char  sorts[CHUNK];   // src-sorted bytes
    __shared__ unsigned short sbkts[CHUNK];   // bucket id per entry (src)

    int tid = threadIdx.x, blk = blockIdx.x;
    if (tid < NB) { hd[tid] = 0; hs[tid] = 0; }
    __syncthreads();

    int e0 = blk * CHUNK, ee = min(e0 + CHUNK, NE);
    int sv[4], dv[4]; bool va[4];
#pragma unroll
    for (int u = 0; u < 4; ++u) {
        int e = e0 + u * BT + tid;
        va[u] = e < ee;
        if (va[u]) {
            sv[u] = src[e]; dv[u] = dst[e];
            atomicAdd(&hd[dv[u] >> 8], 1);
            atomicAdd(&hs[sv[u] >> 8], 1);
        }
    }
    __syncthreads();

    if (tid < 512) {
        t0[tid] = tid < NB ? hd[tid] : 0;
        t1[tid] = tid < NB ? hs[tid] : 0;
    }
    __syncthreads();
    for (int off = 1; off < 512; off <<= 1) {
        int a = 0, b = 0;
        if (tid < 512 && tid >= off) { a = t0[tid - off]; b = t1[tid - off]; }
        __syncthreads();
        if (tid < 512) { t0[tid] += a; t1[tid] += b; }
        __syncthreads();
    }
    if (tid < NB) {
        int c = hd[tid], c2 = hs[tid];
        od[tid] = t0[tid] - c;
        os[tid] = t1[tid] - c2;
        bd[tid] = c  ? atomicAdd(&cur_d[tid], c)  : 0;
        bs[tid] = c2 ? atomicAdd(&cur_s[tid], c2) : 0;
        hd[tid] = od[tid];            // reuse as LDS cursors
        hs[tid] = os[tid];
    }
    __syncthreads();

#pragma unroll
    for (int u = 0; u < 4; ++u) if (va[u]) {
        int bu = dv[u] >> 8;
        int p = atomicAdd(&hd[bu], 1);
        sortd[p] = ((unsigned)(dv[u] & 255) << 17) | (unsigned)sv[u];
        sbkt[p]  = (unsigned short)bu;
        int bv = sv[u] >> 8;
        int q = atomicAdd(&hs[bv], 1);
        sorts[q] = (unsigned char)(sv[u] & 255);
        sbkts[q] = (unsigned short)bv;
    }
    __syncthreads();

    int n = ee - e0;
    for (int i = tid; i < n; i += BT) {
        int b1 = sbkt[i];
        bkd[b1 * ASTR + bd[b1] + (i - od[b1])] = sortd[i];
        int b2 = sbkts[i];
        bks[b2 * ASTR + bs[b2] + (i - os[b2])] = sorts[i];
    }
}

// ---------------------------------------------------------------------------
// B2 (FUSED scanb+p2d+p2s+norm), 1024 threads (R13/R14/R16, passing).
// ---------------------------------------------------------------------------
__global__ __launch_bounds__(PT) void k_p2(const unsigned* __restrict__ bkd,
                                           const unsigned char* __restrict__ bks,
                                           const int* __restrict__ cur_d,
                                           const int* __restrict__ cur_s,
                                           int* __restrict__ cd,
                                           int* __restrict__ start,
                                           int* __restrict__ csr_s,
                                           float* __restrict__ dis,
                                           float* __restrict__ disg) {
    __shared__ int hist[256], scn[256], hsA[256];
    __shared__ int red[PT];
    int b = blockIdx.x, tid = threadIdx.x;
    if (tid < 256) { hist[tid] = 0; hsA[tid] = 0; }
    int acc = 0;
    for (int i = tid; i < b; i += PT) acc += cur_d[i];
    red[tid] = acc;
    __syncthreads();
    for (int off = PT / 2; off > 0; off >>= 1) {
        if (tid < off) red[tid] += red[tid + off];
        __syncthreads();
    }
    int cb = red[0];

    int eb = b * ASTR, ee = eb + cur_d[b];
    for (int e = eb + tid; e < ee; e += PT)
        atomicAdd(&hist[bkd[e] >> 17], 1);
    int sb = b * ASTR, se = sb + cur_s[b];
    for (int e = sb + tid; e < se; e += PT)
        atomicAdd(&hsA[bks[e]], 1);
    __syncthreads();
    int c = (tid < 256) ? hist[tid] : 0;
    if (tid < 256) scn[tid] = c;
    __syncthreads();
    for (int off = 1; off < 256; off <<= 1) {
        int t = (tid < 256 && tid >= off) ? scn[tid - off] : 0;
        __syncthreads();
        if (tid < 256) scn[tid] += t;
        __syncthreads();
    }
    if (tid < 256) {
        int excl = scn[tid] - c;
        int node = (b << 8) + tid;
        if (node < NN) {
            cd[node] = c;
            start[node] = cb + excl;
            int oc = hsA[tid];
            dis[node]  = oc > 0 ? rsqrtf((float)oc) : 0.0f;
            disg[node] = rsqrtf((float)c + 1.0f);
        }
    }
    __syncthreads();              // all hsA reads done
    if (tid < 256) hsA[tid] = cb + scn[tid] - c;   // reuse as csr cursor
    __syncthreads();
    for (int e = eb + tid; e < ee; e += PT) {
        unsigned pk = bkd[e];
        int p = atomicAdd(&hsA[pk >> 17], 1);
        csr_s[p] = (int)(pk & 0x1FFFFu);
    }
}

// ---------------------------------------------------------------------------
// K_cvt (+wcvt in the extra block): SINGLE merged fp16 table (R14, passing).
// ---------------------------------------------------------------------------
__global__ __launch_bounds__(256) void k_cvt(const float* __restrict__ x,
                                             const float* __restrict__ dis,
                                             unsigned short* __restrict__ xs,
                                             const float* __restrict__ W_xz,
                                             const float* __restrict__ W_xh,
                                             const float* __restrict__ W_gcn,
                                             unsigned short* __restrict__ BzT,
                                             unsigned short* __restrict__ BhT,
                                             unsigned short* __restrict__ WgT) {
    int tid = threadIdx.x;
    int i = blockIdx.x * 256 + tid;
    if (i < NN * 32) {
        xs[i] = h16(x[i] * dis[i >> 5]);
    } else if (blockIdx.x == (NN * 32) / 256) {
        for (int idx = tid; idx < 2048; idx += 256) {
            int f = idx >> 6, k = idx & 63;
            float vz = (k < 32) ? W_xz[k * 32 + f] : W_xz[1024 + (k - 32) * 32 + f];
            float vh = (k < 32) ? W_xh[k * 32 + f] : W_xh[1024 + (k - 32) * 32 + f];
            BzT[idx] = h16(vz);
            BhT[idx] = h16(vh);
        }
        for (int idx = tid; idx < 1024; idx += 256) {
            int f = idx >> 5, k = idx & 31;
            WgT[idx] = h16(W_gcn[k * 32 + f]);
        }
    }
}

// ---------------------------------------------------------------------------
// K_gath_lx: merged single-pass gather.  Main loop (16 edges/iter) uses
// PACKED fp16 accumulation (v_pk_add_f16 via __hadd2): 8 pk_add + 8 flush
// ops per 16 edges vs ~36 cvt/add before.  fp16 partials hold <=16 terms
// (drift ~1e-3, scaled by dis ~0.25 downstream).  Masked f32 tail.
// ---------------------------------------------------------------------------
__global__ __launch_bounds__(256) void k_gath_lx(const uint2* __restrict__ xs2,
                                                 const int* __restrict__ csr_s,
                                                 const int* __restrict__ start,
                                                 const int* __restrict__ cd,
                                                 const float* __restrict__ dis,
                                                 unsigned* __restrict__ Lxh) {
    int tid = threadIdx.x;
    int node = blockIdx.x * 8 + (tid >> 5);
    int lane = tid & 31, eoff = lane >> 3, c = lane & 7;
    int st = start[node], cn = cd[node];

    float a0 = 0.f, a1 = 0.f, a2 = 0.f, a3 = 0.f;
    int j = 0;
    for (; j + 16 <= cn; j += 16) {        // unmasked, packed-fp16 partials
        int s0 = csr_s[st + j + eoff];
        int s1 = csr_s[st + j + 4 + eoff];
        int s2 = csr_s[st + j + 8 + eoff];
        int s3 = csr_s[st + j + 12 + eoff];
        uint2 v0 = xs2[s0 * 8 + c];
        uint2 v1 = xs2[s1 * 8 + c];
        uint2 v2 = xs2[s2 * 8 + c];
        uint2 v3 = xs2[s3 * 8 + c];
        __half2 p01 = u2h2(0u), p23 = u2h2(0u);
        p01 = __hadd2(p01, u2h2(v0.x));  p23 = __hadd2(p23, u2h2(v0.y));
        p01 = __hadd2(p01, u2h2(v1.x));  p23 = __hadd2(p23, u2h2(v1.y));
        p01 = __hadd2(p01, u2h2(v2.x));  p23 = __hadd2(p23, u2h2(v2.y));
        p01 = __hadd2(p01, u2h2(v3.x));  p23 = __hadd2(p23, u2h2(v3.y));
        a0 += __low2float(p01);  a1 += __high2float(p01);
        a2 += __low2float(p23);  a3 += __high2float(p23);
    }
    while (j < cn) {                       // masked f32 tail (<=2 batches)
        int e0 = j + eoff, e1 = j + 4 + eoff;
        int c0 = e0 < cn ? e0 : cn - 1;  float m0 = e0 < cn ? 1.0f : 0.0f;
        int c1 = e1 < cn ? e1 : cn - 1;  float m1 = e1 < cn ? 1.0f : 0.0f;
        int s0 = csr_s[st + c0], s1 = csr_s[st + c1];
        uint2 v0 = xs2[s0 * 8 + c];
        uint2 v1 = xs2[s1 * 8 + c];
        a0 = fmaf(m0, h16lo(v0.x), a0);  a1 = fmaf(m0, h16hi(v0.x), a1);
        a2 = fmaf(m0, h16lo(v0.y), a2);  a3 = fmaf(m0, h16hi(v0.y), a3);
        a0 = fmaf(m1, h16lo(v1.x), a0);  a1 = fmaf(m1, h16hi(v1.x), a1);
        a2 = fmaf(m1, h16lo(v1.y), a2);  a3 = fmaf(m1, h16hi(v1.y), a3);
        j += 8;
    }
#pragma unroll
    for (int off = 8; off < 32; off <<= 1) {
        a0 += __shfl_xor(a0, off, 32);  a1 += __shfl_xor(a1, off, 32);
        a2 += __shfl_xor(a2, off, 32);  a3 += __shfl_xor(a3, off, 32);
    }
    if (lane < 8) {      // c == lane; features 4c..4c+3
        float w = -dis[node];
        Lxh[node * 16 + 2 * lane]     = pack2h(w * a0, w * a1);
        Lxh[node * 16 + 2 * lane + 1] = pack2h(w * a2, w * a3);
    }
}

// ---------------------------------------------------------------------------
// K_dmm: MFMA dense phase (R14/R16, passing).
// ---------------------------------------------------------------------------
__global__ __launch_bounds__(256) void k_dmm(
        const float* __restrict__ x,
        const f16x8* __restrict__ Lxh,    // [node*4 + (c-2)*2 + hi]
        const f16x8* __restrict__ BzT,
        const f16x8* __restrict__ BhT,
        const f16x8* __restrict__ WgT,
        const float* __restrict__ b_xz, const float* __restrict__ b_hz,
        const float* __restrict__ b_xh, const float* __restrict__ b_hh,
        const float* __restrict__ disg,
        unsigned short* __restrict__ hws) {
    __shared__ unsigned short Hl[4 * 1280];   // per-wave 32 x 40 u16 (80B pad)
    int tid = threadIdx.x;
    int wv = blockIdx.x * 4 + (tid >> 6);
    if (wv > 3124) wv = 3124;                 // dup tail wave: same writes, safe
    int l = tid & 63, mrow = l & 31, hi = l >> 5;
    int n0 = wv * 32;
    unsigned short* Hw = Hl + (tid >> 6) * 1280;

    f32x16 accz = {}, acct = {};
    const float* xrow = x + (size_t)(n0 + mrow) * 32;
#pragma unroll
    for (int c = 0; c < 2; ++c) {
        f16x8 a;
        const float* p = xrow + c * 16 + hi * 8;
#pragma unroll
        for (int e = 0; e < 8; ++e) a[e] = (_Float16)p[e];
        accz = __builtin_amdgcn_mfma_f32_32x32x16_f16(a, BzT[mrow * 8 + c * 2 + hi], accz, 0, 0, 0);
        acct = __builtin_amdgcn_mfma_f32_32x32x16_f16(a, BhT[mrow * 8 + c * 2 + hi], acct, 0, 0, 0);
    }
    const f16x8* Lrow = Lxh + (size_t)(n0 + mrow) * 4;
#pragma unroll
    for (int c = 2; c < 4; ++c) {
        f16x8 a = Lrow[(c - 2) * 2 + hi];
        accz = __builtin_amdgcn_mfma_f32_32x32x16_f16(a, BzT[mrow * 8 + c * 2 + hi], accz, 0, 0, 0);
        acct = __builtin_amdgcn_mfma_f32_32x32x16_f16(a, BhT[mrow * 8 + c * 2 + hi], acct, 0, 0, 0);
    }
    float bz = b_xz[mrow] + b_hz[mrow];
    float bh = b_xh[mrow] + b_hh[mrow];
#pragma unroll
    for (int j = 0; j < 16; ++j) {
        float z = accz[j] + bz, t = acct[j] + bh;
        float Z = 1.0f / (1.0f + expf(-z));
        float H = (1.0f - Z) * tanhf(t);
        int r = (j & 3) + 8 * (j >> 2) + 4 * hi;
        Hw[r * 40 + mrow] = h16(H);          // H^T staging (row=node, col=f)
    }
    f32x16 acch = {};
#pragma unroll
    for (int c = 0; c < 2; ++c) {
        f16x8 hfrag = *reinterpret_cast<const f16x8*>(&Hw[mrow * 40 + c * 16 + hi * 8]);
        acch = __builtin_amdgcn_mfma_f32_32x32x16_f16(hfrag, WgT[mrow * 4 + c * 2 + hi], acch, 0, 0, 0);
    }
#pragma unroll
    for (int j = 0; j < 16; ++j) {
        int r = (j & 3) + 8 * (j >> 2) + 4 * hi;
        int node = n0 + r;
        hws[node * 32 + mrow] = h16(disg[node] * acch[j]);
    }
}

// ---------------------------------------------------------------------------
// K_gath_h: merged gather + full fused epilogue; packed-fp16 main loop.
// ---------------------------------------------------------------------------
__global__ __launch_bounds__(256) void k_gath_h(const uint2* __restrict__ hws2,
                                                const int* __restrict__ csr_s,
                                                const int* __restrict__ start,
                                                const int* __restrict__ cd,
                                                const float* __restrict__ disg,
                                                const float* __restrict__ b_gcn,
                                                const float* __restrict__ W_lin,
                                                const float* __restrict__ b_lin,
                                                float* __restrict__ out) {
    int tid = threadIdx.x;
    int node = blockIdx.x * 8 + (tid >> 5);
    int lane = tid & 31, eoff = lane >> 3, c = lane & 7;
    int st = start[node], cn = cd[node];

    float a0 = 0.f, a1 = 0.f, a2 = 0.f, a3 = 0.f;
    int j = 0;
    for (; j + 16 <= cn; j += 16) {        // unmasked, packed-fp16 partials
        int s0 = csr_s[st + j + eoff];
        int s1 = csr_s[st + j + 4 + eoff];
        int s2 = csr_s[st + j + 8 + eoff];
        int s3 = csr_s[st + j + 12 + eoff];
        uint2 v0 = hws2[s0 * 8 + c];
        uint2 v1 = hws2[s1 * 8 + c];
        uint2 v2 = hws2[s2 * 8 + c];
        uint2 v3 = hws2[s3 * 8 + c];
        __half2 p01 = u2h2(0u), p23 = u2h2(0u);
        p01 = __hadd2(p01, u2h2(v0.x));  p23 = __hadd2(p23, u2h2(v0.y));
        p01 = __hadd2(p01, u2h2(v1.x));  p23 = __hadd2(p23, u2h2(v1.y));
        p01 = __hadd2(p01, u2h2(v2.x));  p23 = __hadd2(p23, u2h2(v2.y));
        p01 = __hadd2(p01, u2h2(v3.x));  p23 = __hadd2(p23, u2h2(v3.y));
        a0 += __low2float(p01);  a1 += __high2float(p01);
        a2 += __low2float(p23);  a3 += __high2float(p23);
    }
    while (j < cn) {                       // masked f32 tail (<=2 batches)
        int e0 = j + eoff, e1 = j + 4 + eoff;
        int c0 = e0 < cn ? e0 : cn - 1;  float m0 = e0 < cn ? 1.0f : 0.0f;
        int c1 = e1 < cn ? e1 : cn - 1;  float m1 = e1 < cn ? 1.0f : 0.0f;
        int s0 = csr_s[st + c0], s1 = csr_s[st + c1];
        uint2 v0 = hws2[s0 * 8 + c];
        uint2 v1 = hws2[s1 * 8 + c];
        a0 = fmaf(m0, h16lo(v0.x), a0);  a1 = fmaf(m0, h16hi(v0.x), a1);
        a2 = fmaf(m0, h16lo(v0.y), a2);  a3 = fmaf(m0, h16hi(v0.y), a3);
        a0 = fmaf(m1, h16lo(v1.x), a0);  a1 = fmaf(m1, h16hi(v1.x), a1);
        a2 = fmaf(m1, h16lo(v1.y), a2);  a3 = fmaf(m1, h16hi(v1.y), a3);
        j += 8;
    }
#pragma unroll
    for (int off = 8; off < 32; off <<= 1) {
        a0 += __shfl_xor(a0, off, 32);  a1 += __shfl_xor(a1, off, 32);
        a2 += __shfl_xor(a2, off, 32);  a3 += __shfl_xor(a3, off, 32);
    }
    float p = 0.0f;
    if (lane < 8) {      // c == lane; features f0 = 4c
        uint2 sv = hws2[node * 8 + lane];   // self row (pre-scaled by disg)
        float dg = disg[node];
        int f0 = 4 * lane;
        float h0 = dg * (a0 + h16lo(sv.x)) + b_gcn[f0];
        float h1 = dg * (a1 + h16hi(sv.x)) + b_gcn[f0 + 1];
        float h2 = dg * (a2 + h16lo(sv.y)) + b_gcn[f0 + 2];
        float h3 = dg * (a3 + h16hi(sv.y)) + b_gcn[f0 + 3];
        p = fmaxf(h0, 0.0f) * W_lin[f0]
          + fmaxf(h1, 0.0f) * W_lin[f0 + 1]
          + fmaxf(h2, 0.0f) * W_lin[f0 + 2]
          + fmaxf(h3, 0.0f) * W_lin[f0 + 3];
    }
    p += __shfl_xor(p, 1, 32);
    p += __shfl_xor(p, 2, 32);
    p += __shfl_xor(p, 4, 32);
    if (lane == 0) out[node] = p + b_lin[0];
}

extern "C" void kernel_launch(void* const* d_in, const int* in_sizes, int n_in,
                              void* d_out, int out_size, void* d_ws, size_t ws_size,
                              hipStream_t stream) {
    const float* x     = (const float*)d_in[0];
    const int*   ei    = (const int*)d_in[1];
    const int*   src   = ei;
    const int*   dst   = ei + NE;
    const float* W_xz  = (const float*)d_in[2];
    const float* b_xz  = (const float*)d_in[3];
    const float* b_hz  = (const float*)d_in[5];
    // W_xr/b_xr/W_hr/b_hr (d_in[6..9]) are dead: R only multiplies H0 == 0.
    const float* W_xh  = (const float*)d_in[10];
    const float* b_xh  = (const float*)d_in[11];
    const float* b_hh  = (const float*)d_in[13];
    const float* W_gcn = (const float*)d_in[14];
    const float* b_gcn = (const float*)d_in[15];
    const float* W_lin = (const float*)d_in[16];
    const float* b_lin = (const float*)d_in[17];
    float* out = (float*)d_out;

    // Workspace (4B words), ~36.8 MB (R14 layout).  cur_d/cur_s zeroed by
    // k_zero (was hipMemsetAsync -> 44us fillBufferAligned in profile).
    // Aliases: xs (16N words) overlays bkd arena (dead after k_p2).
    int* w = (int*)d_ws;
    int* cur_d = w;                       w += 392;
    int* cur_s = w;                       w += 392;
    int* cd    = w;                       w += NN;
    int* start = w;                       w += NN;
    float* dis  = (float*)w;              w += NN;
    float* disg = (float*)w;              w += NN;
    unsigned short* hws = (unsigned short*)w;  w += 16 * NN;    // 32 fp16/node
    unsigned* Lxh = (unsigned*)w;         w += 16 * NN;         // 32 fp16/node
    unsigned* bkd = (unsigned*)w;         w += NB * ASTR;       // 3,203,072
    unsigned char* bks = (unsigned char*)w; w += (NB * ASTR) / 4;
    int* csr_s = w;                       w += NE;
    unsigned short* BzT = (unsigned short*)w; w += 1024;        // 32f x 64k
    unsigned short* BhT = (unsigned short*)w; w += 1024;
    unsigned short* WgT = (unsigned short*)w; w += 512;         // 32f x 32k
    unsigned short* xs = (unsigned short*)bkd;                  // alias

    k_zero   <<<1, 1024, 0, stream>>>(cur_d);
    k_bucket <<<NBLK, BT, 0, stream>>>(src, dst, cur_d, cur_s, bkd, bks);
    k_p2     <<<NB, PT, 0, stream>>>(bkd, bks, cur_d, cur_s,
                                     cd, start, csr_s, dis, disg);
    k_cvt    <<<(NN * 32) / 256 + 1, 256, 0, stream>>>(x, dis, xs,
                                      W_xz, W_xh, W_gcn, BzT, BhT, WgT);
    k_gath_lx<<<NN / 8, 256, 0, stream>>>((const uint2*)xs, csr_s, start, cd,
                                          dis, Lxh);
    k_dmm    <<<782, 256, 0, stream>>>(x, (const f16x8*)Lxh, (const f16x8*)BzT,
                                       (const f16x8*)BhT, (const f16x8*)WgT,
                                       b_xz, b_hz, b_xh, b_hh, disg, hws);
    k_gath_h <<<NN / 8, 256, 0, stream>>>((const uint2*)hws, csr_s, start, cd,
                                          disg, b_gcn, W_lin, b_lin, out);
}